// Round 8
// baseline (326.932 us; speedup 1.0000x reference)
//
#include <hip/hip_runtime.h>
#include <stdint.h>

using f32x4   = __attribute__((ext_vector_type(4))) float;
using short8  = __attribute__((ext_vector_type(8))) short;
using float2v = __attribute__((ext_vector_type(2))) float;
using uint4v  = __attribute__((ext_vector_type(4))) unsigned int;

#define NCOL 11008
#define KDIM 4096
#define KSEG 4        // K-split factor: 64 kbs -> 4 segments of 16
#define KB_PER_SEG 16
#define TILE_B 8192   // W tile: 64 k-rows x 32 cols fp32 = 64*128 B

#define AS1 __attribute__((address_space(1)))
#define AS3 __attribute__((address_space(3)))

__device__ __forceinline__ unsigned pk_bf16(float a, float b) {
  unsigned ua = __float_as_uint(a); ua += 0x7fffu + ((ua >> 16) & 1u);  // RNE
  unsigned ub = __float_as_uint(b); ub += 0x7fffu + ((ub >> 16) & 1u);
  return (ua >> 16) | (ub & 0xffff0000u);
}

// ---- kernel 1: mask (fp64-exact; verified green) + write mask-zeroed bf16
//      copy of x into ws. grid (8 rb, 8 kgrp), 256 thr. UNCHANGED.
__global__ __launch_bounds__(256) void mask_convert_kernel(
    const float* __restrict__ x, unsigned* __restrict__ xbf) {
  const int rb = blockIdx.x;
  const int g  = blockIdx.y;
  const int t  = threadIdx.x;
  __shared__ double part[256];
  __shared__ unsigned sh_bits;

  const float* base = x + (size_t)rb * 16 * KDIM + g * 512 + t * 2;
  double s = 0.0;
#pragma unroll
  for (int r = 0; r < 16; ++r) {
    float2v a = *(const float2v*)(base + (size_t)r * KDIM);
    s += (double)fabsf(a[0]) + (double)fabsf(a[1]);
  }
  part[t] = s;
  __syncthreads();
  if (t < 8) {                        // t = kb-local (8 kbs per 512-col group)
    double acc = 0.0;
#pragma unroll
    for (int u = 0; u < 32; ++u) acc += part[t * 32 + u];
    bool on = (acc * (1.0 / 1024.0)) > (double)0.8f;
    unsigned long long bal = __ballot(on);
    if (t == 0) sh_bits = (unsigned)(bal & 0xffu);
  }
  __syncthreads();
  const unsigned keep = (sh_bits >> (t >> 5)) & 1u;

  unsigned* dst = xbf + (size_t)rb * 16 * (KDIM / 2) + g * 256 + t;
#pragma unroll
  for (int r = 0; r < 16; ++r) {      // reload (L1-hot) + pack/zero + store
    float2v a = *(const float2v*)(base + (size_t)r * KDIM);
    dst[(size_t)r * (KDIM / 2)] = keep ? pk_bf16(a[0], a[1]) : 0u;
  }
}

// ---- kernel 1b: out[r][n] = bias[n] so gemm ksegs can atomically accumulate
// order-free. grid (43, 128): 11008 = 43*256 cols, 128 rows.
__global__ __launch_bounds__(256) void bias_init_kernel(
    const float* __restrict__ bias, float* __restrict__ out) {
  const int n = blockIdx.x * 256 + threadIdx.x;
  out[(size_t)blockIdx.y * NCOL + n] = bias[n];
}

// ---- kernel 1c: W pre-touch — contiguous grid-stride read of all 180 MB
// of W into Infinity Cache (memory-side, allocate-on-read). The gemm's
// strided 128-B-granule stream then hits L3 instead of DRAM: per-request
// latency drops ~2-4x, and with fixed in-flight bytes per phase the
// staging BW rises proportionally (Little's law). ~30 us at stream BW.
// asm keep-alive prevents DCE (rule #17).
__global__ __launch_bounds__(256) void touch_w_kernel(
    const uint4v* __restrict__ w4) {
  const size_t n = (size_t)KDIM * NCOL / 4;           // 11,272,192 uint4
  const size_t stride = (size_t)gridDim.x * 256;
  for (size_t i = (size_t)blockIdx.x * 256 + threadIdx.x; i < n; i += stride) {
    uint4v v = w4[i];
    asm volatile("" :: "v"(v[0]), "v"(v[1]), "v"(v[2]), "v"(v[3]));
  }
}

// ---- kernel 2: dense GEMM on masked bf16 x. grid (344, KSEG=4), 256 thr.
// Byte-identical to the R6-verified kernel EXCEPT the k-visit order:
// block bx walks its 16 kbs rotated by (bx & 15). R7 post-mortem: the
// ~1.5 TB/s staging plateau across ALL execution structures is memory-side
// channel camping — W rows at 44032-B stride map to ~10-13 of 32 channels
// per 64-row phase window (channel(k) = floor(43k/4) mod 32 under 4-KB
// interleave), and all 344 blocks camp the same subset in phase-lockstep
// (kseg offset 5504 = 0 mod 32). Rotation de-phases stripes across the
// 128-row channel cycle -> instantaneous demand covers all channels.
__global__ __launch_bounds__(256) void gemm_kernel(
    const unsigned* __restrict__ xbf, const float* __restrict__ w,
    float* __restrict__ out) {

  __shared__ __align__(16) uint8_t lds[2 * TILE_B];

  const int tid  = threadIdx.x;
  const int lane = tid & 63;
  const int wv   = tid >> 6;
  const int c    = lane & 15;
  const int q    = lane >> 4;
  const int n0   = blockIdx.x * 32;
  const int kb0  = blockIdx.y * KB_PER_SEG;
  const int rot  = blockIdx.x & 15;   // channel de-camping rotation

#define KBI(i) (kb0 + (((i) + rot) & 15))

  f32x4 acc[2][2] = {};               // [band][even/odd]

  // W staging geometry: thread t covers, for round r in {0,1}:
  //   LDS byte L = r*4096 + wv*1024 + lane*16  ->  row k = r*32 + (t>>3),
  //   byte-in-row (t&7)*16; global: W[kb*64 + k][n0 + (t&7)*4 ..+3]
  const int kA = tid >> 3;            // 0..31
  const int cB = (tid & 7) * 4;       // float col offset in tile row
  const float* gW = w + (size_t)kA * NCOL + n0 + cB;

#define STAGE(PBUF, KBI_)                                                    \
  {                                                                          \
    const float* g_ = gW + (size_t)(KBI_) * 64 * NCOL;                       \
    __builtin_amdgcn_global_load_lds(                                        \
        (const AS1 void*)g_,                                                 \
        (AS3 void*)(lds + (PBUF) * TILE_B + wv * 1024), 16, 0, 0);           \
    __builtin_amdgcn_global_load_lds(                                        \
        (const AS1 void*)(g_ + (size_t)32 * NCOL),                           \
        (AS3 void*)(lds + (PBUF) * TILE_B + 4096 + wv * 1024), 16, 0, 0);    \
  }

  // A source (bf16 masked x, L2-resident): uint4v idx = row*512 + kb*8 + ks*4 + q
  const uint4v* aB0 = (const uint4v*)xbf + (size_t)((wv * 2 + 0) * 16 + c) * (KDIM / 8) + q;
  const uint4v* aB1 = (const uint4v*)xbf + (size_t)((wv * 2 + 1) * 16 + c) * (KDIM / 8) + q;

  auto compute = [&](const uint8_t* buf, int kbi) {
    union { uint4v u; short8 v; } a00, a01, a10, a11;
    a00.u = aB0[kbi * 8 + 0];        // band0 ks=0
    a01.u = aB0[kbi * 8 + 4];        // band0 ks=1
    a10.u = aB1[kbi * 8 + 0];        // band1 ks=0
    a11.u = aB1[kbi * 8 + 4];        // band1 ks=1

#pragma unroll
    for (int ks = 0; ks < 2; ++ks) {
      // rows k = ks*32 + q*8 + j hold cols (2c, 2c+1) as float2 at byte k*128 + c*8
      const uint8_t* wb = buf + (size_t)(ks * 32 + q * 8) * 128 + c * 8;
      float2v r[8];
#pragma unroll
      for (int j = 0; j < 8; ++j)
        r[j] = *(const float2v*)(wb + (size_t)j * 128);
      union { short8 v; unsigned u[4]; } be, bo;
#pragma unroll
      for (int p = 0; p < 4; ++p) {
        be.u[p] = pk_bf16(r[2 * p][0], r[2 * p + 1][0]);   // even col 2c
        bo.u[p] = pk_bf16(r[2 * p][1], r[2 * p + 1][1]);   // odd  col 2c+1
      }
      const short8 a0 = ks ? a01.v : a00.v;
      const short8 a1 = ks ? a11.v : a10.v;
      acc[0][0] = __builtin_amdgcn_mfma_f32_16x16x32_bf16(a0, be.v, acc[0][0], 0, 0, 0);
      acc[0][1] = __builtin_amdgcn_mfma_f32_16x16x32_bf16(a0, bo.v, acc[0][1], 0, 0, 0);
      acc[1][0] = __builtin_amdgcn_mfma_f32_16x16x32_bf16(a1, be.v, acc[1][0], 0, 0, 0);
      acc[1][1] = __builtin_amdgcn_mfma_f32_16x16x32_bf16(a1, bo.v, acc[1][1], 0, 0, 0);
    }
  };

  // prologue: stage first tile, drain
  STAGE(0, KBI(0));
  __syncthreads();

  int p = 0;
  for (int i = 0; i < KB_PER_SEG; ++i) {
    if (i + 1 < KB_PER_SEG) STAGE(p ^ 1, KBI(i + 1));  // in flight during compute
    compute(lds + p * TILE_B, KBI(i));
    __syncthreads();               // retires stage(i+1); guards buf reuse
    p ^= 1;
  }
#undef STAGE
#undef KBI

  // epilogue: D row = band*16 + q*4 + pp, cols (2c,2c+1); native fp32
  // atomic add (relaxed, agent scope). 4 ksegs per address, lane-disjoint.
  const int colE = n0 + 2 * c;
#pragma unroll
  for (int b = 0; b < 2; ++b) {
#pragma unroll
    for (int pp = 0; pp < 4; ++pp) {
      const int row = (wv * 2 + b) * 16 + q * 4 + pp;
      float* pdst = out + (size_t)row * NCOL + colE;
      __hip_atomic_fetch_add(pdst,     acc[b][0][pp], __ATOMIC_RELAXED,
                             __HIP_MEMORY_SCOPE_AGENT);
      __hip_atomic_fetch_add(pdst + 1, acc[b][1][pp], __ATOMIC_RELAXED,
                             __HIP_MEMORY_SCOPE_AGENT);
    }
  }
}

extern "C" void kernel_launch(void* const* d_in, const int* in_sizes, int n_in,
                              void* d_out, int out_size, void* d_ws, size_t ws_size,
                              hipStream_t stream) {
  const float* x    = (const float*)d_in[0];
  const float* w    = (const float*)d_in[1];
  const float* bias = (const float*)d_in[2];
  float* out        = (float*)d_out;
  unsigned* xbf     = (unsigned*)d_ws;    // 128 x 4096 bf16 (1 MiB)

  hipLaunchKernelGGL(mask_convert_kernel, dim3(8, 8), dim3(256), 0, stream, x, xbf);
  hipLaunchKernelGGL(bias_init_kernel, dim3(43, 128), dim3(256), 0, stream, bias, out);
  hipLaunchKernelGGL(touch_w_kernel, dim3(2048), dim3(256), 0, stream,
                     (const uint4v*)w);
  hipLaunchKernelGGL(gemm_kernel, dim3(344, KSEG), dim3(256), 0, stream,
                     xbf, w, out);
}

// Round 9
// 287.460 us; speedup vs baseline: 1.1373x; 1.1373x over previous
//
#include <hip/hip_runtime.h>
#include <stdint.h>

using f32x4   = __attribute__((ext_vector_type(4))) float;
using short8  = __attribute__((ext_vector_type(8))) short;
using float2v = __attribute__((ext_vector_type(2))) float;
using uint4v  = __attribute__((ext_vector_type(4))) unsigned int;

#define NCOL 11008
#define KDIM 4096
#define KSEG 4        // K-split: 64 kbs -> 4 segments of 16
#define KB_PER_SEG 16
#define RING_B 24576  // ring slot: 8 KB W (fp32 64x32) + 16 KB A (128x128B)

#define AS1 __attribute__((address_space(1)))
#define AS3 __attribute__((address_space(3)))

__device__ __forceinline__ unsigned pk_bf16(float a, float b) {
  unsigned ua = __float_as_uint(a); ua += 0x7fffu + ((ua >> 16) & 1u);  // RNE
  unsigned ub = __float_as_uint(b); ub += 0x7fffu + ((ub >> 16) & 1u);
  return (ua >> 16) | (ub & 0xffff0000u);
}

// ---- kernel 1: mask (fp64-exact; verified green) + write mask-zeroed bf16
//      copy of x into ws. grid (8 rb, 8 kgrp), 256 thr. UNCHANGED.
__global__ __launch_bounds__(256) void mask_convert_kernel(
    const float* __restrict__ x, unsigned* __restrict__ xbf) {
  const int rb = blockIdx.x;
  const int g  = blockIdx.y;
  const int t  = threadIdx.x;
  __shared__ double part[256];
  __shared__ unsigned sh_bits;

  const float* base = x + (size_t)rb * 16 * KDIM + g * 512 + t * 2;
  double s = 0.0;
#pragma unroll
  for (int r = 0; r < 16; ++r) {
    float2v a = *(const float2v*)(base + (size_t)r * KDIM);
    s += (double)fabsf(a[0]) + (double)fabsf(a[1]);
  }
  part[t] = s;
  __syncthreads();
  if (t < 8) {
    double acc = 0.0;
#pragma unroll
    for (int u = 0; u < 32; ++u) acc += part[t * 32 + u];
    bool on = (acc * (1.0 / 1024.0)) > (double)0.8f;
    unsigned long long bal = __ballot(on);
    if (t == 0) sh_bits = (unsigned)(bal & 0xffu);
  }
  __syncthreads();
  const unsigned keep = (sh_bits >> (t >> 5)) & 1u;

  unsigned* dst = xbf + (size_t)rb * 16 * (KDIM / 2) + g * 256 + t;
#pragma unroll
  for (int r = 0; r < 16; ++r) {
    float2v a = *(const float2v*)(base + (size_t)r * KDIM);
    dst[(size_t)r * (KDIM / 2)] = keep ? pk_bf16(a[0], a[1]) : 0u;
  }
}

// ---- kernel 1b: out[r][n] = bias[n] so gemm ksegs accumulate order-free.
__global__ __launch_bounds__(256) void bias_init_kernel(
    const float* __restrict__ bias, float* __restrict__ out) {
  const int n = blockIdx.x * 256 + threadIdx.x;
  out[(size_t)blockIdx.y * NCOL + n] = bias[n];
}

// ---- kernel 2: dense GEMM. grid (344, KSEG=4), 256 thr (4 waves).
// M=128 x N=32, 16 kbs/block. NEW (the untested matrix cell): ALL vmem is
// gl_lds (W as in R6; A now staged to LDS too, source-XOR-swizzled so the
// dest stays linear), with COUNTED asm vmcnt + raw lgkm-barrier — so load
// groups for phases j,j+1 stay in flight ACROSS phases (depth-2, ring-3
// LDS, ONE barrier per phase, never vmcnt(0) in the main loop). R0-R8
// post-mortem: every prior round drained vmem to zero each phase (reg
// prefetch was compiler-sunk; __syncthreads drains vmcnt), so each phase
// re-paid full queue latency (~1.2us) -> the invariant ~103us. A-loads
// must NOT be compiler reg-loads: their auto-waitcnts would drain our
// counted pipeline (asm resets the compiler's vm tracking).
__global__ __launch_bounds__(256) void gemm_kernel(
    const unsigned* __restrict__ xbf, const float* __restrict__ w,
    float* __restrict__ out) {

  __shared__ __align__(16) uint8_t lds[3 * RING_B];

  const int tid  = threadIdx.x;
  const int lane = tid & 63;
  const int wv   = tid >> 6;
  const int c    = lane & 15;
  const int q    = lane >> 4;
  const int n0   = blockIdx.x * 32;
  const int kb0  = blockIdx.y * KB_PER_SEG;

  f32x4 acc[2][2] = {};               // [band][even/odd]

  // W staging (R6-verbatim geometry): lane covers row kA=tid>>3 (and +32),
  // col chunk (tid&7)*4; dest linear [64][128B] at wave-uniform base.
  const int kA = tid >> 3;
  const int cB = (tid & 7) * 4;
  const float* gW = w + (size_t)kA * NCOL + n0 + cB;

  // A staging: wave wv, instr t covers rows r = wv*32+t*8+(lane>>3), 16B
  // chunk u=(lane&7) XOR-swizzled by (r&7)=(lane>>3) in the SOURCE (dest
  // linear [128][128B] per gl_lds rule); read side applies the same XOR.
  const unsigned swz = ((unsigned)(lane & 7) ^ (unsigned)(lane >> 3)) << 4;
  const uint8_t* gA = (const uint8_t*)xbf + swz;

#define ISSUE_GROUP(RB, KBI)                                                  \
  {                                                                           \
    uint8_t* base_ = lds + (RB) * RING_B;                                     \
    const float* g_ = gW + (size_t)(KBI) * 64 * NCOL;                         \
    __builtin_amdgcn_global_load_lds((const AS1 void*)g_,                     \
        (AS3 void*)(base_ + wv * 1024), 16, 0, 0);                            \
    __builtin_amdgcn_global_load_lds((const AS1 void*)(g_ + (size_t)32*NCOL), \
        (AS3 void*)(base_ + 4096 + wv * 1024), 16, 0, 0);                     \
    _Pragma("unroll")                                                         \
    for (int t_ = 0; t_ < 4; ++t_) {                                          \
      const int r_ = wv * 32 + t_ * 8 + (lane >> 3);                          \
      __builtin_amdgcn_global_load_lds(                                       \
          (const AS1 void*)(gA + (size_t)r_ * 8192 + (size_t)(KBI) * 128),    \
          (AS3 void*)(base_ + 8192 + wv * 4096 + t_ * 1024), 16, 0, 0);       \
    }                                                                         \
  }

#define WAITV(N)                                                              \
  { asm volatile("s_waitcnt vmcnt(" #N ")" ::: "memory");                     \
    __builtin_amdgcn_sched_barrier(0); }
#define BAR()                                                                 \
  { asm volatile("s_waitcnt lgkmcnt(0)" ::: "memory");                        \
    __builtin_amdgcn_s_barrier(); __builtin_amdgcn_sched_barrier(0); }

  auto compute = [&](const uint8_t* buf) {
    const uint8_t* Ab = buf + 8192;
#pragma unroll
    for (int ks = 0; ks < 2; ++ks) {
      union { uint4v u; short8 v; } a0, a1;
      {
        const int row0 = (wv * 2 + 0) * 16 + c;
        const int row1 = (wv * 2 + 1) * 16 + c;
        const int sl0 = (ks * 4 + q) ^ (row0 & 7);
        const int sl1 = (ks * 4 + q) ^ (row1 & 7);
        a0.u = *(const uint4v*)(Ab + (size_t)row0 * 128 + sl0 * 16);
        a1.u = *(const uint4v*)(Ab + (size_t)row1 * 128 + sl1 * 16);
      }
      // W rows k = ks*32 + q*8 + j, cols (2c,2c+1) as float2 at k*128 + c*8
      const uint8_t* wb = buf + (size_t)(ks * 32 + q * 8) * 128 + c * 8;
      float2v r[8];
#pragma unroll
      for (int j = 0; j < 8; ++j)
        r[j] = *(const float2v*)(wb + (size_t)j * 128);
      union { short8 v; unsigned u[4]; } be, bo;
#pragma unroll
      for (int p = 0; p < 4; ++p) {
        be.u[p] = pk_bf16(r[2 * p][0], r[2 * p + 1][0]);   // even col 2c
        bo.u[p] = pk_bf16(r[2 * p][1], r[2 * p + 1][1]);   // odd  col 2c+1
      }
      acc[0][0] = __builtin_amdgcn_mfma_f32_16x16x32_bf16(a0.v, be.v, acc[0][0], 0, 0, 0);
      acc[0][1] = __builtin_amdgcn_mfma_f32_16x16x32_bf16(a0.v, bo.v, acc[0][1], 0, 0, 0);
      acc[1][0] = __builtin_amdgcn_mfma_f32_16x16x32_bf16(a1.v, be.v, acc[1][0], 0, 0, 0);
      acc[1][1] = __builtin_amdgcn_mfma_f32_16x16x32_bf16(a1.v, bo.v, acc[1][1], 0, 0, 0);
    }
  };

  // prologue: group 0 in flight (depth builds to 2 inside the loop)
  ISSUE_GROUP(0, kb0);

#pragma unroll
  for (int j = 0; j < KB_PER_SEG; ++j) {
    if (j + 1 < KB_PER_SEG) {
      ISSUE_GROUP((j + 1) % 3, kb0 + j + 1);   // 2 groups (12 instr) in flight
      WAITV(6);                                // group j complete; j+1 flying
    } else {
      WAITV(0);                                // last group
    }
    BAR();                                     // LDS visibility, no vm drain
    compute(lds + (j % 3) * RING_B);
  }
#undef ISSUE_GROUP
#undef WAITV
#undef BAR

  // epilogue: D row = band*16 + q*4 + pp, cols (2c,2c+1); fp32 atomic add
  // (relaxed, agent). 4 ksegs per address, lane-disjoint.
  const int colE = n0 + 2 * c;
#pragma unroll
  for (int b = 0; b < 2; ++b) {
#pragma unroll
    for (int pp = 0; pp < 4; ++pp) {
      const int row = (wv * 2 + b) * 16 + q * 4 + pp;
      float* pdst = out + (size_t)row * NCOL + colE;
      __hip_atomic_fetch_add(pdst,     acc[b][0][pp], __ATOMIC_RELAXED,
                             __HIP_MEMORY_SCOPE_AGENT);
      __hip_atomic_fetch_add(pdst + 1, acc[b][1][pp], __ATOMIC_RELAXED,
                             __HIP_MEMORY_SCOPE_AGENT);
    }
  }
}

extern "C" void kernel_launch(void* const* d_in, const int* in_sizes, int n_in,
                              void* d_out, int out_size, void* d_ws, size_t ws_size,
                              hipStream_t stream) {
  const float* x    = (const float*)d_in[0];
  const float* w    = (const float*)d_in[1];
  const float* bias = (const float*)d_in[2];
  float* out        = (float*)d_out;
  unsigned* xbf     = (unsigned*)d_ws;    // 128 x 4096 bf16 (1 MiB)

  hipLaunchKernelGGL(mask_convert_kernel, dim3(8, 8), dim3(256), 0, stream, x, xbf);
  hipLaunchKernelGGL(bias_init_kernel, dim3(43, 128), dim3(256), 0, stream, bias, out);
  hipLaunchKernelGGL(gemm_kernel, dim3(344, KSEG), dim3(256), 0, stream,
                     xbf, w, out);
}